// Round 16
// baseline (1210.519 us; speedup 1.0000x reference)
//
#include <hip/hip_runtime.h>
#include <hip/hip_bf16.h>

// Problem constants
#define NB    65536      // batch rows
#define KDIM  1024       // reduction dim for all projections
#define NDIM  1024       // output dim per projection

#define BK 32
#define NT (KDIM / BK)   // 32 K-tiles (even)

typedef float f32x4  __attribute__((ext_vector_type(4)));
typedef short short8 __attribute__((ext_vector_type(8)));
typedef unsigned short ushort8v __attribute__((ext_vector_type(8)));

static __device__ __forceinline__ unsigned short f2bf(float f) {
    union { float f; unsigned u; } v; v.f = f;
    unsigned r = v.u + 0x7FFFu + ((v.u >> 16) & 1u);
    return (unsigned short)(r >> 16);
}
static __device__ __forceinline__ float bf2f(unsigned short h) {
    union { unsigned u; float f; } v; v.u = ((unsigned)h) << 16;
    return v.f;
}

// async global->LDS, 16B per lane. LDS dest = wave-uniform base + lane*16.
static __device__ __forceinline__ void gload16(const unsigned short* g, unsigned short* l) {
    __builtin_amdgcn_global_load_lds(
        (const __attribute__((address_space(1))) unsigned int*)g,
        (__attribute__((address_space(3))) unsigned int*)l, 16, 0, 0);
}

// ---------------------------------------------------------------------------
// PACKED LAYOUT (GEMM-consumption order; r10: cold 64B-scatter caps at
// 1.98 TB/s; r11: packing -> 900+ TF streaming):
//   1KB chunk index = ((r>>8)*32 + t)*16 + ((r>>4)&15)
//   inner (shorts)  = kc*128 + (r&15)*8 + pos
// A chunk read at lane*16B IS one complete 16-row x 32-k MFMA fragment set.
// ---------------------------------------------------------------------------

// ONE pack dispatch for all 6 fp32->packed-bf16 conversions (r15-verified).
__global__ __launch_bounds__(256) void pack_all_k(
    const float* __restrict__ latent, const float* __restrict__ cond,
    const float* __restrict__ Wq, const float* __restrict__ Wk,
    const float* __restrict__ Wv, const float* __restrict__ Wout,
    unsigned short* __restrict__ Lp, unsigned short* __restrict__ Cp,
    unsigned short* __restrict__ wqp, unsigned short* __restrict__ wkvp,
    unsigned short* __restrict__ wop)
{
    const int b = blockIdx.x;
    const float* src; unsigned short* dst; int rb;
    if (b < 4096)      { src = latent; dst = Lp;              rb = b; }
    else if (b < 8192) { src = cond;   dst = Cp;              rb = b - 4096; }
    else if (b < 8256) { src = Wq;     dst = wqp;             rb = b - 8192; }
    else if (b < 8320) { src = Wk;     dst = wkvp;            rb = b - 8256; }
    else if (b < 8384) { src = Wv;     dst = wkvp + 1048576;  rb = b - 8320; }
    else               { src = Wout;   dst = wop;             rb = b - 8384; }

    const int tid = threadIdx.x;
    const int r   = rb * 16 + (tid >> 4);
    const int cb  = (tid & 15) * 64;
    const int p   = r >> 8;
    const int f   = (r >> 4) & 15;
    const int rl  = r & 15;
    const float* s = src + (size_t)r * 1024 + cb;
#pragma unroll
    for (int g = 0; g < 8; ++g) {
        float4 va = *reinterpret_cast<const float4*>(s + g * 8);
        float4 vb = *reinterpret_cast<const float4*>(s + g * 8 + 4);
        ushort8v o;
        o[0] = f2bf(va.x); o[1] = f2bf(va.y); o[2] = f2bf(va.z); o[3] = f2bf(va.w);
        o[4] = f2bf(vb.x); o[5] = f2bf(vb.y); o[6] = f2bf(vb.z); o[7] = f2bf(vb.w);
        const int c0 = cb + g * 8;
        const int t  = c0 >> 5;
        const int kc = (c0 & 31) >> 3;
        *reinterpret_cast<ushort8v*>(
            &dst[((size_t)(p * 32 + t) * 16 + f) * 512 + kc * 128 + rl * 8]) = o;
    }
}

// ---------------------------------------------------------------------------
// GEMM core v2 -- HYBRID OPERAND DELIVERY (r15 post-mortem arithmetic:
// tile = MFMA 1243 + LDS-reads 1150 + DMA 256 + tails = 2787 cyc, additive).
// A: streamed global->register (packed chunk @ lane*16B = the fragment; the
//    4 waves sharing wm read IDENTICAL addresses -> L1-served; prefetched
//    one tile ahead in named even/odd reg sets, compiler counted-vmcnt).
// B: gload_lds ring-2 (16 KB/tile), r8-proven {stage(t+1); reads; MFMA;
//    vmcnt(0); barrier} cadence.
// New LDS term: 32 KB reads + 16 KB DMA ~= 510 cyc -> predicted ~1900/tile.
// Overwrite safety: STAGE B(t+1)->slot^1 issued after barrier(t-1), at which
// slot^1's tile t-1 reads completed (lgkm-before-MFMA). vmcnt(0) at tile end
// validates B(t+1) and drains A(t+1) reg loads (issued ~1 tile earlier).
// 512 thr = 8 waves (2 wm x 4 wn), per-wave output 128x64.
// ---------------------------------------------------------------------------
typedef unsigned short ringT[2][16][512];   // 32 KB

static __device__ __forceinline__ void gemm_core2(
    const unsigned short* __restrict__ Ap, const unsigned short* __restrict__ Wp,
    int pA, int pB, int lane, int wid, int wm, int wn,
    unsigned short* smem, f32x4 (&acc)[8][4])
{
    ringT& ring = *reinterpret_cast<ringT*>(smem);
    const unsigned short* baseA =
        Ap + ((size_t)(pA * 32) * 16 + wm * 8) * 512 + lane * 8;

#define STAGEB_(TAU, SLOT) do {                                                 \
        _Pragma("unroll")                                                       \
        for (int _j = 0; _j < 2; ++_j) {                                        \
            int _f = wid * 2 + _j;                                              \
            gload16(Wp + ((size_t)(pB * 32 + (TAU)) * 16 + _f) * 512 + lane * 8,\
                    &ring[SLOT][_f][0]);                                        \
        }                                                                       \
    } while (0)

#define LOADA_(T, AA) do {                                                      \
        _Pragma("unroll")                                                       \
        for (int _mi = 0; _mi < 8; ++_mi)                                       \
            AA[_mi] = *reinterpret_cast<const short8*>(                         \
                baseA + (size_t)(T) * 8192 + _mi * 512);                        \
    } while (0)

#define READB_(SLOT, BQ) do {                                                   \
        _Pragma("unroll")                                                       \
        for (int _ni = 0; _ni < 4; ++_ni)                                       \
            BQ[_ni] = *reinterpret_cast<const short8*>(                         \
                &ring[SLOT][wn * 4 + _ni][lane * 8]);                           \
    } while (0)

#define MFMA_(AA, BQ) do {                                                      \
        __builtin_amdgcn_s_setprio(1);                                          \
        _Pragma("unroll")                                                       \
        for (int _mi = 0; _mi < 8; ++_mi)                                       \
            _Pragma("unroll")                                                   \
            for (int _ni = 0; _ni < 4; ++_ni)                                   \
                acc[_mi][_ni] = __builtin_amdgcn_mfma_f32_16x16x32_bf16(        \
                    AA[_mi], BQ[_ni], acc[_mi][_ni], 0, 0, 0);                  \
        __builtin_amdgcn_s_setprio(0);                                          \
    } while (0)

    short8 aA[8], aB[8], bq[4];

    // prologue: A(0) regs + B(0) staged
    LOADA_(0, aA);
    STAGEB_(0, 0);
    asm volatile("s_waitcnt vmcnt(0)" ::: "memory");
    __builtin_amdgcn_s_barrier();

#pragma unroll 1
    for (int tt = 0; tt < NT; tt += 2) {
        // even: compute tile tt (aA, B slot 0); prefetch tt+1
        LOADA_(tt + 1, aB);                  // tt+1 <= 31 always valid
        STAGEB_(tt + 1, 1);
        READB_(0, bq);
        MFMA_(aA, bq);
        asm volatile("s_waitcnt vmcnt(0)" ::: "memory");
        __builtin_amdgcn_s_barrier();

        // odd: compute tile tt+1 (aB, B slot 1); prefetch tt+2
        if (tt + 2 < NT) { LOADA_(tt + 2, aA); STAGEB_(tt + 2, 0); }
        READB_(1, bq);
        MFMA_(aB, bq);
        asm volatile("s_waitcnt vmcnt(0)" ::: "memory");
        __builtin_amdgcn_s_barrier();
    }
#undef STAGEB_
#undef LOADA_
#undef READB_
#undef MFMA_
}

// ---------------------------------------------------------------------------
// MERGED Q + KV projection GEMM (r15 structure): blocks [0,1024) = Q
// (Lp @ wqp -> Qb, NN=1024); [1024,3072) = KV (Cp @ wkvp -> KVb, NN=2048).
// ---------------------------------------------------------------------------
__global__ __launch_bounds__(512, 2) void gemm_qkv(
    const unsigned short* __restrict__ Lp, const unsigned short* __restrict__ Cp,
    const unsigned short* __restrict__ wqp, const unsigned short* __restrict__ wkvp,
    unsigned short* __restrict__ Qb, unsigned short* __restrict__ KVb)
{
    __shared__ alignas(16) unsigned short smem[33792];  // ring 32KB | bounce 66KB union

    const int t    = threadIdx.x;
    const int lane = t & 63;
    const int wid  = t >> 6;
    const int wm   = wid >> 2;
    const int wn   = wid & 3;

    const int nwg  = gridDim.x;              // 3072
    const int cpx  = nwg >> 3;
    const int orig = blockIdx.x;
    const int wgid = (orig & 7) * cpx + (orig >> 3);

    const unsigned short* Ap; const unsigned short* Wp;
    unsigned short* Cb; int NN, bn0, bm0;
    if (wgid < 1024) {                       // Q segment, GN=4
        Ap = Lp; Wp = wqp; Cb = Qb; NN = 1024;
        bn0 = (wgid & 3) * 256; bm0 = (wgid >> 2) * 256;
    } else {                                 // KV segment, GN=8
        int w2 = wgid - 1024;
        Ap = Cp; Wp = wkvp; Cb = KVb; NN = 2048;
        bn0 = (w2 & 7) * 256; bm0 = (w2 >> 3) * 256;
    }
    const int pA = bm0 >> 8, pB = bn0 >> 8;

    f32x4 acc[8][4];
#pragma unroll
    for (int mi = 0; mi < 8; ++mi)
#pragma unroll
        for (int ni = 0; ni < 4; ++ni)
            acc[mi][ni] = (f32x4){0.f, 0.f, 0.f, 0.f};

    gemm_core2(Ap, Wp, pA, pB, lane, wid, wm, wn, smem, acc);

    // bf16 epilogue: LDS bounce -> full-line stores (r7+: WRITE exact-ideal)
    const int crow = (lane >> 4) * 4;
    const int ccol = lane & 15;
    unsigned short* bb = smem;
#pragma unroll
    for (int p = 0; p < 2; ++p) {
        if (wm == p) {
#pragma unroll
            for (int ml = 0; ml < 8; ++ml)
#pragma unroll
                for (int ni = 0; ni < 4; ++ni)
#pragma unroll
                    for (int r = 0; r < 4; ++r)
                        bb[(ml * 16 + crow + r) * 264 + wn * 64 + ni * 16 + ccol]
                            = f2bf(acc[ml][ni][r]);
        }
        __syncthreads();
#pragma unroll
        for (int it = 0; it < 8; ++it) {
            int lrow = wid * 16 + it * 2 + (lane >> 5);
            int lcol = (lane & 31) * 8;
            ushort8v v = *reinterpret_cast<const ushort8v*>(&bb[lrow * 264 + lcol]);
            *reinterpret_cast<ushort8v*>(
                &Cb[(size_t)(bm0 + p * 128 + lrow) * NN + bn0 + lcol]) = v;
        }
        __syncthreads();
    }
}

// ---------------------------------------------------------------------------
// Output projection: packed feats @ packed Wout^T + bias -> fp32 out.
// ---------------------------------------------------------------------------
__global__ __launch_bounds__(512, 2) void gemm_out(
    const unsigned short* __restrict__ Fp, const unsigned short* __restrict__ wop,
    const float* __restrict__ bias, float* __restrict__ Cf)
{
    constexpr int NN = 1024;
    __shared__ alignas(16) unsigned short smem[34304];  // ring 32KB | f32 bounce union

    const int t    = threadIdx.x;
    const int lane = t & 63;
    const int wid  = t >> 6;
    const int wm   = wid >> 2;
    const int wn   = wid & 3;

    const int nwg  = gridDim.x;              // 1024
    const int cpx  = nwg >> 3;
    const int orig = blockIdx.x;
    const int wgid = (orig & 7) * cpx + (orig >> 3);
    const int bn0  = (wgid & 3) * 256;
    const int bm0  = (wgid >> 2) * 256;
    const int pA = bm0 >> 8, pB = bn0 >> 8;

    f32x4 acc[8][4];
#pragma unroll
    for (int mi = 0; mi < 8; ++mi)
#pragma unroll
        for (int ni = 0; ni < 4; ++ni)
            acc[mi][ni] = (f32x4){0.f, 0.f, 0.f, 0.f};

    gemm_core2(Fp, wop, pA, pB, lane, wid, wm, wn, smem, acc);

    // fp32 epilogue with bias (r12/r15 verbatim)
    const int crow = (lane >> 4) * 4;
    const int ccol = lane & 15;
    float* bbf = reinterpret_cast<float*>(smem);
    float bv[4];
#pragma unroll
    for (int ni = 0; ni < 4; ++ni)
        bv[ni] = bias[bn0 + wn * 64 + ni * 16 + ccol];
#pragma unroll
    for (int p = 0; p < 4; ++p) {
        if (wm == (p >> 1)) {
#pragma unroll
            for (int ml = 0; ml < 4; ++ml)
#pragma unroll
                for (int ni = 0; ni < 4; ++ni)
#pragma unroll
                    for (int r = 0; r < 4; ++r)
                        bbf[(ml * 16 + crow + r) * 268 + wn * 64 + ni * 16 + ccol]
                            = acc[(p & 1) * 4 + ml][ni][r] + bv[ni];
        }
        __syncthreads();
#pragma unroll
        for (int it = 0; it < 8; ++it) {
            int lrow = wid * 8 + it;
            f32x4 v = *reinterpret_cast<const f32x4*>(&bbf[lrow * 268 + lane * 4]);
            *reinterpret_cast<f32x4*>(
                &Cf[(size_t)(bm0 + p * 64 + lrow) * NN + bn0 + lane * 4]) = v;
        }
        __syncthreads();
    }
}

// ---------------------------------------------------------------------------
// Per-row attention, 16 rows/block (16 waves), wave-per-row body (r12/r15
// verbatim). Reads Q row-major + fused KV (stride 2048); writes feats PACKED.
// ---------------------------------------------------------------------------
__global__ __launch_bounds__(1024) void attn_k(
    const unsigned short* __restrict__ Qb, const unsigned short* __restrict__ KVb,
    unsigned short* __restrict__ Fp)
{
    __shared__ alignas(16) unsigned short KL[16][1024];   // K rows; reused as feats
    __shared__ alignas(16) unsigned short VL[16][1024];
    const int t = threadIdx.x;
    const int lane = t & 63;
    const int wid = t >> 6;                       // 0..15
    const size_t row = (size_t)blockIdx.x * 16 + wid;
    const size_t base = row * 1024;
    const size_t bkv  = row * 2048;
    const int off = lane * 16;

    ushort8v q0 = *reinterpret_cast<const ushort8v*>(&Qb[base + off]);
    ushort8v q1 = *reinterpret_cast<const ushort8v*>(&Qb[base + off + 8]);
    float qf[16];
#pragma unroll
    for (int j = 0; j < 8; ++j) { qf[j] = bf2f(q0[j]); qf[8 + j] = bf2f(q1[j]); }

    *reinterpret_cast<ushort8v*>(&KL[wid][off])     = *reinterpret_cast<const ushort8v*>(&KVb[bkv + off]);
    *reinterpret_cast<ushort8v*>(&KL[wid][off + 8]) = *reinterpret_cast<const ushort8v*>(&KVb[bkv + off + 8]);
    *reinterpret_cast<ushort8v*>(&VL[wid][off])     = *reinterpret_cast<const ushort8v*>(&KVb[bkv + 1024 + off]);
    *reinterpret_cast<ushort8v*>(&VL[wid][off + 8]) = *reinterpret_cast<const ushort8v*>(&KVb[bkv + 1024 + off + 8]);
    __syncthreads();

    const int sub = lane & 3;
    float s[16];
#pragma unroll
    for (int g = 0; g < 16; ++g) {
        const ushort8v k0 = *reinterpret_cast<const ushort8v*>(&KL[wid][g * 64 + sub * 16]);
        const ushort8v k1 = *reinterpret_cast<const ushort8v*>(&KL[wid][g * 64 + sub * 16 + 8]);
        float acc = 0.f;
#pragma unroll
        for (int j = 0; j < 8; ++j)
            acc += qf[j] * bf2f(k0[j]) + qf[8 + j] * bf2f(k1[j]);
        s[g] = acc;
    }
#pragma unroll
    for (int m = 1; m <= 2; m <<= 1)
#pragma unroll
        for (int g = 0; g < 16; ++g)
            s[g] += __shfl_xor(s[g], m, 64);

    float mx = s[0];
#pragma unroll
    for (int g = 1; g < 16; ++g) mx = fmaxf(mx, s[g]);
    float p[16], denom = 0.f;
#pragma unroll
    for (int g = 0; g < 16; ++g) {
        p[g] = __expf((s[g] - mx) * 0.125f);
        denom += p[g];
    }
    float inv = 1.f / denom;

    float f[16];
#pragma unroll
    for (int j = 0; j < 16; ++j) f[j] = 0.f;
#pragma unroll
    for (int g = 0; g < 16; ++g) {
        float pg = p[g] * inv;
        const ushort8v v0 = *reinterpret_cast<const ushort8v*>(&VL[wid][g * 64 + sub * 16]);
        const ushort8v v1 = *reinterpret_cast<const ushort8v*>(&VL[wid][g * 64 + sub * 16 + 8]);
#pragma unroll
        for (int j = 0; j < 8; ++j) {
            f[j]     += pg * bf2f(v0[j]);
            f[8 + j] += pg * bf2f(v1[j]);
        }
    }
    ushort8v o0, o1;
#pragma unroll
    for (int j = 0; j < 8; ++j) { o0[j] = f2bf(f[j]); o1[j] = f2bf(f[8 + j]); }
    *reinterpret_cast<ushort8v*>(&KL[wid][off])     = o0;
    *reinterpret_cast<ushort8v*>(&KL[wid][off + 8]) = o1;
    __syncthreads();

    // cooperative packed write: block = f-stripe (p, f); 32KB total
    const int r0 = blockIdx.x * 16;
    const int pp = r0 >> 8;
    const int ff = (r0 >> 4) & 15;
    const int tt = t >> 5;          // tile 0..31
    const int kc = (t >> 3) & 3;    // k-chunk 0..3
    const int rp = t & 7;           // row pair 0..7
    unsigned short* db = &Fp[((size_t)(pp * 32 + tt) * 16 + ff) * 512 + kc * 128 + rp * 16];
    *reinterpret_cast<ushort8v*>(db)     = *reinterpret_cast<const ushort8v*>(&KL[rp * 2][tt * 32 + kc * 8]);
    *reinterpret_cast<ushort8v*>(db + 8) = *reinterpret_cast<const ushort8v*>(&KL[rp * 2 + 1][tt * 32 + kc * 8]);
}

// ---------------------------------------------------------------------------
extern "C" void kernel_launch(void* const* d_in, const int* in_sizes, int n_in,
                              void* d_out, int out_size, void* d_ws, size_t ws_size,
                              hipStream_t stream)
{
    (void)in_sizes; (void)n_in; (void)out_size; (void)ws_size;
    const float* latent = (const float*)d_in[0];
    const float* cond   = (const float*)d_in[1];
    const float* Wq     = (const float*)d_in[2];
    const float* Wk     = (const float*)d_in[3];
    const float* Wv     = (const float*)d_in[4];
    const float* Wout   = (const float*)d_in[5];
    const float* bout   = (const float*)d_in[6];
    float* out = (float*)d_out;

    char* ws = (char*)d_ws;
    const size_t MB = 1ull << 20;
    unsigned short* wqp  = (unsigned short*)(ws + 0 * MB);    // 2 MB packed Wq
    unsigned short* wkvp = (unsigned short*)(ws + 2 * MB);    // 4 MB packed [Wk;Wv]
    unsigned short* wop  = (unsigned short*)(ws + 6 * MB);    // 2 MB packed Wout
    unsigned short* Qb   = (unsigned short*)(ws + 8 * MB);    // 128 MB row-major Q
    unsigned short* KVb  = (unsigned short*)(ws + 136 * MB);  // 256 MB row-major fused K|V
    unsigned short* Lp   = (unsigned short*)(ws + 392 * MB);  // 128 MB packed latent; reused as packed feats
    unsigned short* Cp   = (unsigned short*)(ws + 520 * MB);  // 128 MB packed cond
    unsigned short* Fp   = Lp;                                // Lp dead after QKV GEMM

    // 1) all packs in one dispatch (8448 blocks)
    pack_all_k<<<8448, 256, 0, stream>>>(latent, cond, Wq, Wk, Wv, Wout,
                                         Lp, Cp, wqp, wkvp, wop);

    // 2) merged Q + KV projections (3072 blocks)
    gemm_qkv<<<3072, 512, 0, stream>>>(Lp, Cp, wqp, wkvp, Qb, KVb);

    // 3) attention: row-major Q/KV in, PACKED feats out (into Fp = Lp)
    attn_k<<<NB / 16, 1024, 0, stream>>>(Qb, KVb, Fp);

    // 4) output projection
    gemm_out<<<1024, 512, 0, stream>>>(Fp, wop, bout, out);
}